// Round 3
// baseline (408.963 us; speedup 1.0000x reference)
//
#include <hip/hip_runtime.h>
#include <hip/hip_fp16.h>
#include <hip/hip_bf16.h>
#include <math.h>

#define T_LEN 1024
#define D_DIM 64
#define BATCH 32

#define SLACK_FRONT 64                      // rows of +INF (half) before each matrix
#define SLACK_BACK  72                      // in-bounds don't-care rows at the end
#define ROW_STRIDE  (T_LEN + SLACK_FRONT)   // 1088 rows per batch segment
#define PD 8                                // prefetch depth (steps)

typedef __attribute__((ext_vector_type(2))) _Float16 h2v;

// ---------------------------------------------------------------------------
// Fill the 64-row front-slack region of each batch segment with half(+INF).
// Re-run every launch (harness re-poisons d_ws). 4 MB total.
// one uint4 (8 halves) per thread: 32 regions x 8192 uint4.
// ---------------------------------------------------------------------------
__global__ __launch_bounds__(256) void fill_slack_kernel(__half* __restrict__ ws) {
    int g = blockIdx.x * 256 + threadIdx.x;      // 0 .. 262143
    int b = g >> 13;                             // 8192 uint4 per slack region
    int off = g & 8191;
    uint4* dst = (uint4*)(ws + (size_t)b * ((size_t)ROW_STRIDE * T_LEN)) + off;
    *dst = make_uint4(0x7C007C00u, 0x7C007C00u, 0x7C007C00u, 0x7C007C00u);
}

// ---------------------------------------------------------------------------
// Pairwise distances, 128x128 tile, 256 threads, 8x8 micro-tile, BK=32 x2.
// Output fp16 (selection-only DP downstream -> error ~ one half ULP).
// ---------------------------------------------------------------------------
__global__ __launch_bounds__(256) void cost_kernel(const float* __restrict__ pred,
                                                   const float* __restrict__ targ,
                                                   __half* __restrict__ cost_base,
                                                   unsigned long long batch_stride_h) {
    const int b = blockIdx.z;
    const float* P = pred + (size_t)b * T_LEN * D_DIM;
    const float* T = targ + (size_t)b * T_LEN * D_DIM;
    __half* C = cost_base + (size_t)b * batch_stride_h;
    const int row0 = blockIdx.y * 128;
    const int col0 = blockIdx.x * 128;

    __shared__ __align__(16) float ps[32][132];  // ps[kk][r] = P[row0+r][k0+kk]
    __shared__ __align__(16) float ts[32][132];
    __shared__ float p2[128], t2[128];

    const int tid = threadIdx.x;

    // Squared norms straight from global (coalesced float4).
    {
        int r = tid & 127;
        const float* src = (tid < 128) ? (P + (size_t)(row0 + r) * D_DIM)
                                       : (T + (size_t)(col0 + r) * D_DIM);
        float s = 0.0f;
#pragma unroll
        for (int q = 0; q < 16; q++) {
            float4 v = ((const float4*)src)[q];
            s += v.x * v.x + v.y * v.y + v.z * v.z + v.w * v.w;
        }
        if (tid < 128) p2[r] = s; else t2[r] = s;
    }

    const int lane = tid & 63, wv = tid >> 6;
    const int TX = (lane & 7) + 8 * (wv & 1);    // 0..15
    const int TY = (lane >> 3) + 8 * (wv >> 1);  // 0..15

    float acc[8][8];
#pragma unroll
    for (int i = 0; i < 8; i++)
#pragma unroll
        for (int j = 0; j < 8; j++) acc[i][j] = 0.0f;

#pragma unroll
    for (int chunk = 0; chunk < 2; ++chunk) {
        __syncthreads();
#pragma unroll
        for (int it = 0; it < 4; ++it) {
            int idx = tid + 256 * it;            // 0..1023
            int row = idx >> 3;                  // 0..127
            int kc = idx & 7;                    // float4 chunk within 32-k
            float4 v = *(const float4*)(P + (size_t)(row0 + row) * D_DIM + 32 * chunk + 4 * kc);
            ps[4 * kc + 0][row] = v.x; ps[4 * kc + 1][row] = v.y;
            ps[4 * kc + 2][row] = v.z; ps[4 * kc + 3][row] = v.w;
            float4 w = *(const float4*)(T + (size_t)(col0 + row) * D_DIM + 32 * chunk + 4 * kc);
            ts[4 * kc + 0][row] = w.x; ts[4 * kc + 1][row] = w.y;
            ts[4 * kc + 2][row] = w.z; ts[4 * kc + 3][row] = w.w;
        }
        __syncthreads();

#pragma unroll
        for (int kk = 0; kk < 32; ++kk) {
            float4 a0 = *(const float4*)&ps[kk][8 * TY];
            float4 a1 = *(const float4*)&ps[kk][8 * TY + 4];
            float4 b0 = *(const float4*)&ts[kk][8 * TX];
            float4 b1 = *(const float4*)&ts[kk][8 * TX + 4];
            float av[8] = {a0.x, a0.y, a0.z, a0.w, a1.x, a1.y, a1.z, a1.w};
            float bv[8] = {b0.x, b0.y, b0.z, b0.w, b1.x, b1.y, b1.z, b1.w};
#pragma unroll
            for (int i = 0; i < 8; i++)
#pragma unroll
                for (int j = 0; j < 8; j++) acc[i][j] += av[i] * bv[j];
        }
    }
    __syncthreads();

#pragma unroll
    for (int i = 0; i < 8; i++) {
        float pa = p2[8 * TY + i];
        h2v o2[4];
#pragma unroll
        for (int j = 0; j < 4; j++) {
            float d0 = pa + t2[8 * TX + 2 * j]     - 2.0f * acc[i][2 * j];
            float d1 = pa + t2[8 * TX + 2 * j + 1] - 2.0f * acc[i][2 * j + 1];
            h2v h;
            h[0] = (_Float16)sqrtf(fmaxf(d0, 1e-12f));
            h[1] = (_Float16)sqrtf(fmaxf(d1, 1e-12f));
            o2[j] = h;
        }
        float4 st;
        st.x = __builtin_bit_cast(float, o2[0]);
        st.y = __builtin_bit_cast(float, o2[1]);
        st.z = __builtin_bit_cast(float, o2[2]);
        st.w = __builtin_bit_cast(float, o2[3]);
        __half* dst = C + (size_t)(row0 + 8 * TY + i) * T_LEN + col0 + 8 * TX;
        *(float4*)dst = st;
    }
}

// ---------------------------------------------------------------------------
// Branchless Frechet DP, one wave per batch, fp16 cost, strided INF slack.
// Per-cell chain = ONE med3: max(c,min(e,x)) == med3(c, max(e,c), x).
// 8-deep register prefetch pipeline PINNED with sched_barrier(0) so the
// scheduler cannot sink the loads (round-2 failure mode: VGPR=96, stalls).
// ---------------------------------------------------------------------------
__global__ __launch_bounds__(64, 1) void dp_kernel_nb(const __half* __restrict__ cost,
                                                      float* __restrict__ out) {
    const int b = blockIdx.x;
    const int t = threadIdx.x;
    const float INF = __builtin_inff();
    const __half* Cl = cost + ((size_t)SLACK_FRONT + (size_t)b * ROW_STRIDE) * T_LEN + 16 * t;

    float prev[16];
#pragma unroll
    for (int j = 0; j < 16; j++) prev[j] = INF;
    float right_out = INF;
    float diag_feed = INF;
    float lane0_left = -INF;   // -INF only for the very first step (r==0,t==0)

    float4 pipe[PD][2];        // 16 halves per row-slice
    const __half* ptr[PD];
#pragma unroll
    for (int d = 0; d < PD; d++) {
        const float4* p4 = (const float4*)(Cl + (ptrdiff_t)(d - t) * T_LEN);
        pipe[d][0] = p4[0]; pipe[d][1] = p4[1];
        ptr[d] = Cl + (ptrdiff_t)(d + PD - t) * T_LEN;
    }

    // 135 chunks of 8 steps = s 0..1079
    for (int chunk = 0; chunk < 135; ++chunk) {
#pragma unroll
        for (int u = 0; u < PD; u++) {
            float inc = __shfl_up(right_out, 1, 64);
            float left = (t == 0) ? lane0_left : inc;
            float diag = (t == 0) ? INF : diag_feed;
            diag_feed = inc;
            // unpack 16 halves (value-based, stays in registers)
            h2v hh[8];
            hh[0] = __builtin_bit_cast(h2v, pipe[u][0].x);
            hh[1] = __builtin_bit_cast(h2v, pipe[u][0].y);
            hh[2] = __builtin_bit_cast(h2v, pipe[u][0].z);
            hh[3] = __builtin_bit_cast(h2v, pipe[u][0].w);
            hh[4] = __builtin_bit_cast(h2v, pipe[u][1].x);
            hh[5] = __builtin_bit_cast(h2v, pipe[u][1].y);
            hh[6] = __builtin_bit_cast(h2v, pipe[u][1].z);
            hh[7] = __builtin_bit_cast(h2v, pipe[u][1].w);
#pragma unroll
            for (int j = 0; j < 16; j++) {
                float c = (float)hh[j >> 1][j & 1];
                float e = fminf(prev[j], diag);                 // off-chain
                float h = fmaxf(e, c);                          // off-chain
                float v = __builtin_amdgcn_fmed3f(c, h, left);  // 1 op on chain
                diag = prev[j];
                prev[j] = v;
                left = v;
            }
            right_out = left;
            lane0_left = INF;
            // PINNED reload of pipe[u] for step s+PD (pure pointer bump)
            __builtin_amdgcn_sched_barrier(0);
            {
                const float4* p4 = (const float4*)ptr[u];
                pipe[u][0] = p4[0]; pipe[u][1] = p4[1];
                ptr[u] += (size_t)PD * T_LEN;
            }
            __builtin_amdgcn_sched_barrier(0);
        }
    }
    // remainder: s = 1080..1086, data already in pipe[0..6], no reloads
#pragma unroll
    for (int u = 0; u < 7; u++) {
        float inc = __shfl_up(right_out, 1, 64);
        float left = (t == 0) ? lane0_left : inc;
        float diag = (t == 0) ? INF : diag_feed;
        diag_feed = inc;
        h2v hh[8];
        hh[0] = __builtin_bit_cast(h2v, pipe[u][0].x);
        hh[1] = __builtin_bit_cast(h2v, pipe[u][0].y);
        hh[2] = __builtin_bit_cast(h2v, pipe[u][0].z);
        hh[3] = __builtin_bit_cast(h2v, pipe[u][0].w);
        hh[4] = __builtin_bit_cast(h2v, pipe[u][1].x);
        hh[5] = __builtin_bit_cast(h2v, pipe[u][1].y);
        hh[6] = __builtin_bit_cast(h2v, pipe[u][1].z);
        hh[7] = __builtin_bit_cast(h2v, pipe[u][1].w);
#pragma unroll
        for (int j = 0; j < 16; j++) {
            float c = (float)hh[j >> 1][j & 1];
            float e = fminf(prev[j], diag);
            float h = fmaxf(e, c);
            float v = __builtin_amdgcn_fmed3f(c, h, left);
            diag = prev[j];
            prev[j] = v;
            left = v;
        }
        right_out = left;
        lane0_left = INF;
    }

    if (t == 63) atomicAdd(out, prev[15] * (1.0f / (float)BATCH));
}

// ---------------------------------------------------------------------------
// Last-resort fused fallback (ws too small for strided fp16 layout).
// ---------------------------------------------------------------------------
__global__ __launch_bounds__(64) void dp_fused_kernel(const float* __restrict__ pred,
                                                      const float* __restrict__ targ,
                                                      float* __restrict__ out) {
    const int b = blockIdx.x;
    const int t = threadIdx.x;
    const float INF = __builtin_inff();
    const float* P = pred + (size_t)b * T_LEN * D_DIM;
    const float* T = targ + (size_t)b * T_LEN * D_DIM + (size_t)(16 * t) * D_DIM;

    float prev[16];
#pragma unroll
    for (int j = 0; j < 16; j++) prev[j] = INF;
    float right_out = INF;
    float diag_feed = INF;

    for (int s = 0; s < T_LEN + 63; s++) {
        int r = s - t;
        float inc = __shfl_up(right_out, 1, 64);
        float left = inc, diag = diag_feed;
        diag_feed = inc;
        if (t == 0) { left = (r == 0) ? -INF : INF; diag = INF; }
        if (r >= 0 && r < T_LEN) {
            float4 pr[16];
            const float4* pp = (const float4*)(P + (size_t)r * D_DIM);
#pragma unroll
            for (int q = 0; q < 16; q++) pr[q] = pp[q];
#pragma unroll
            for (int j = 0; j < 16; j++) {
                const float4* tp = (const float4*)(T + (size_t)j * D_DIM);
                float acc = 0.0f;
#pragma unroll
                for (int q = 0; q < 16; q++) {
                    float4 tv = tp[q];
                    float dx = pr[q].x - tv.x; acc += dx * dx;
                    float dy = pr[q].y - tv.y; acc += dy * dy;
                    float dz = pr[q].z - tv.z; acc += dz * dz;
                    float dw = pr[q].w - tv.w; acc += dw * dw;
                }
                float c = sqrtf(fmaxf(acc, 1e-12f));
                float e = fminf(prev[j], diag);
                float h = fmaxf(e, c);
                float v = __builtin_amdgcn_fmed3f(c, h, left);
                diag = prev[j];
                prev[j] = v;
                left = v;
            }
            right_out = left;
        }
    }
    if (t == 63) atomicAdd(out, prev[15] * (1.0f / (float)BATCH));
}

extern "C" void kernel_launch(void* const* d_in, const int* in_sizes, int n_in,
                              void* d_out, int out_size, void* d_ws, size_t ws_size,
                              hipStream_t stream) {
    const float* pred = (const float*)d_in[0];
    const float* targ = (const float*)d_in[1];
    float* out = (float*)d_out;

    hipMemsetAsync(out, 0, sizeof(float) * out_size, stream);

    const size_t need_strided =
        ((size_t)BATCH * ROW_STRIDE + SLACK_BACK) * (size_t)T_LEN * sizeof(__half);  // ~71.4 MB

    if (ws_size >= need_strided) {
        __half* ws = (__half*)d_ws;
        fill_slack_kernel<<<1024, 256, 0, stream>>>(ws);
        __half* cost_base = ws + (size_t)SLACK_FRONT * T_LEN;
        dim3 grid(8, 8, BATCH);
        cost_kernel<<<grid, 256, 0, stream>>>(pred, targ, cost_base,
                                              (unsigned long long)ROW_STRIDE * T_LEN);
        dp_kernel_nb<<<BATCH, 64, 0, stream>>>(ws, out);
    } else {
        dp_fused_kernel<<<BATCH, 64, 0, stream>>>(pred, targ, out);
    }
}

// Round 4
// 368.496 us; speedup vs baseline: 1.1098x; 1.1098x over previous
//
#include <hip/hip_runtime.h>
#include <hip/hip_fp16.h>
#include <hip/hip_bf16.h>
#include <math.h>

#define T_LEN 1024
#define D_DIM 64
#define BATCH 32

#define SLACK_FRONT 64                      // rows of half(+INF) before each matrix
#define SLACK_BACK  72                      // in-bounds don't-care rows at the end
#define ROW_STRIDE  (T_LEN + SLACK_FRONT)   // 1088 rows per batch segment
#define PD 8                                // prefetch depth (steps)

typedef __attribute__((ext_vector_type(2))) _Float16 h2v;

// ---------------------------------------------------------------------------
// Fill the 64-row front-slack region of each batch segment with half(+INF).
// Re-run every launch (harness re-poisons d_ws). one uint4 (8 halves)/thread.
// ---------------------------------------------------------------------------
__global__ __launch_bounds__(256) void fill_slack_kernel(__half* __restrict__ ws) {
    int g = blockIdx.x * 256 + threadIdx.x;      // 0 .. 262143
    int b = g >> 13;                             // 8192 uint4 per slack region
    int off = g & 8191;
    uint4* dst = (uint4*)(ws + (size_t)b * ((size_t)ROW_STRIDE * T_LEN)) + off;
    *dst = make_uint4(0x7C007C00u, 0x7C007C00u, 0x7C007C00u, 0x7C007C00u);
}

// ---------------------------------------------------------------------------
// Pairwise distances, 128x128 tile, 256 threads, 8x8 micro-tile, BK=32 x2.
// Output fp16 (selection-only DP downstream -> error ~ one half ULP).
// ---------------------------------------------------------------------------
__global__ __launch_bounds__(256) void cost_kernel(const float* __restrict__ pred,
                                                   const float* __restrict__ targ,
                                                   __half* __restrict__ cost_base,
                                                   unsigned long long batch_stride_h) {
    const int b = blockIdx.z;
    const float* P = pred + (size_t)b * T_LEN * D_DIM;
    const float* T = targ + (size_t)b * T_LEN * D_DIM;
    __half* C = cost_base + (size_t)b * batch_stride_h;
    const int row0 = blockIdx.y * 128;
    const int col0 = blockIdx.x * 128;

    __shared__ __align__(16) float ps[32][132];  // ps[kk][r] = P[row0+r][k0+kk]
    __shared__ __align__(16) float ts[32][132];
    __shared__ float p2[128], t2[128];

    const int tid = threadIdx.x;

    // Squared norms straight from global (coalesced float4).
    {
        int r = tid & 127;
        const float* src = (tid < 128) ? (P + (size_t)(row0 + r) * D_DIM)
                                       : (T + (size_t)(col0 + r) * D_DIM);
        float s = 0.0f;
#pragma unroll
        for (int q = 0; q < 16; q++) {
            float4 v = ((const float4*)src)[q];
            s += v.x * v.x + v.y * v.y + v.z * v.z + v.w * v.w;
        }
        if (tid < 128) p2[r] = s; else t2[r] = s;
    }

    const int lane = tid & 63, wv = tid >> 6;
    const int TX = (lane & 7) + 8 * (wv & 1);    // 0..15
    const int TY = (lane >> 3) + 8 * (wv >> 1);  // 0..15

    float acc[8][8];
#pragma unroll
    for (int i = 0; i < 8; i++)
#pragma unroll
        for (int j = 0; j < 8; j++) acc[i][j] = 0.0f;

#pragma unroll
    for (int chunk = 0; chunk < 2; ++chunk) {
        __syncthreads();
#pragma unroll
        for (int it = 0; it < 4; ++it) {
            int idx = tid + 256 * it;            // 0..1023
            int row = idx >> 3;                  // 0..127
            int kc = idx & 7;                    // float4 chunk within 32-k
            float4 v = *(const float4*)(P + (size_t)(row0 + row) * D_DIM + 32 * chunk + 4 * kc);
            ps[4 * kc + 0][row] = v.x; ps[4 * kc + 1][row] = v.y;
            ps[4 * kc + 2][row] = v.z; ps[4 * kc + 3][row] = v.w;
            float4 w = *(const float4*)(T + (size_t)(col0 + row) * D_DIM + 32 * chunk + 4 * kc);
            ts[4 * kc + 0][row] = w.x; ts[4 * kc + 1][row] = w.y;
            ts[4 * kc + 2][row] = w.z; ts[4 * kc + 3][row] = w.w;
        }
        __syncthreads();

#pragma unroll
        for (int kk = 0; kk < 32; ++kk) {
            float4 a0 = *(const float4*)&ps[kk][8 * TY];
            float4 a1 = *(const float4*)&ps[kk][8 * TY + 4];
            float4 b0 = *(const float4*)&ts[kk][8 * TX];
            float4 b1 = *(const float4*)&ts[kk][8 * TX + 4];
            float av[8] = {a0.x, a0.y, a0.z, a0.w, a1.x, a1.y, a1.z, a1.w};
            float bv[8] = {b0.x, b0.y, b0.z, b0.w, b1.x, b1.y, b1.z, b1.w};
#pragma unroll
            for (int i = 0; i < 8; i++)
#pragma unroll
                for (int j = 0; j < 8; j++) acc[i][j] += av[i] * bv[j];
        }
    }
    __syncthreads();

#pragma unroll
    for (int i = 0; i < 8; i++) {
        float pa = p2[8 * TY + i];
        h2v o2[4];
#pragma unroll
        for (int j = 0; j < 4; j++) {
            float d0 = pa + t2[8 * TX + 2 * j]     - 2.0f * acc[i][2 * j];
            float d1 = pa + t2[8 * TX + 2 * j + 1] - 2.0f * acc[i][2 * j + 1];
            h2v h;
            h[0] = (_Float16)sqrtf(fmaxf(d0, 1e-12f));
            h[1] = (_Float16)sqrtf(fmaxf(d1, 1e-12f));
            o2[j] = h;
        }
        float4 st;
        st.x = __builtin_bit_cast(float, o2[0]);
        st.y = __builtin_bit_cast(float, o2[1]);
        st.z = __builtin_bit_cast(float, o2[2]);
        st.w = __builtin_bit_cast(float, o2[3]);
        __half* dst = C + (size_t)(row0 + 8 * TY + i) * T_LEN + col0 + 8 * TX;
        *(float4*)dst = st;
    }
}

// ---------------------------------------------------------------------------
// Branchless Frechet DP, one wave per batch, fp16 cost, strided INF slack.
// FULLY SCALARIZED: no loop-carried arrays (rounds 1-3: pipe[]/ptr[] went to
// scratch -> full memory latency per step, VGPR_Count 60-96 proved it).
// Per-cell chain = ONE med3: max(c,min(e,x)) == med3(c, max(e,c), x).
// ---------------------------------------------------------------------------

// one DP cell; pv_ is the running "up" value for this column (updated in place)
#define CELL(c_, pv_) { \
    float c = (c_); \
    float e = fminf(pv_, diag); \
    float hm = fmaxf(e, c); \
    float vv = __builtin_amdgcn_fmed3f(c, hm, left); \
    diag = pv_; pv_ = vv; left = vv; }

// one skew step consuming pipeline slot (PA,PB) = 16 fp16 costs
#define DP_STEP(PA, PB) { \
    float inc = __shfl_up(right_out, 1, 64); \
    float left = (t == 0) ? lane0_left : inc; \
    float diag = (t == 0) ? INF : diag_feed; \
    diag_feed = inc; \
    h2v u0 = __builtin_bit_cast(h2v, PA.x), u1 = __builtin_bit_cast(h2v, PA.y); \
    h2v u2 = __builtin_bit_cast(h2v, PA.z), u3 = __builtin_bit_cast(h2v, PA.w); \
    h2v u4 = __builtin_bit_cast(h2v, PB.x), u5 = __builtin_bit_cast(h2v, PB.y); \
    h2v u6 = __builtin_bit_cast(h2v, PB.z), u7 = __builtin_bit_cast(h2v, PB.w); \
    CELL((float)u0[0], v0)  CELL((float)u0[1], v1) \
    CELL((float)u1[0], v2)  CELL((float)u1[1], v3) \
    CELL((float)u2[0], v4)  CELL((float)u2[1], v5) \
    CELL((float)u3[0], v6)  CELL((float)u3[1], v7) \
    CELL((float)u4[0], v8)  CELL((float)u4[1], v9) \
    CELL((float)u5[0], v10) CELL((float)u5[1], v11) \
    CELL((float)u6[0], v12) CELL((float)u6[1], v13) \
    CELL((float)u7[0], v14) CELL((float)u7[1], v15) \
    right_out = left; lane0_left = INF; }

#define RELOAD(n) { \
    const float4* p4 = (const float4*)q##n; \
    a##n = p4[0]; b##n = p4[1]; \
    q##n += (size_t)PD * T_LEN; }

#define INIT_SLOT(n) { \
    const float4* p4 = (const float4*)(Cl + (ptrdiff_t)(n - t) * T_LEN); \
    a##n = p4[0]; b##n = p4[1]; \
    q##n = Cl + (ptrdiff_t)(n + PD - t) * T_LEN; }

__global__ __launch_bounds__(64, 1) void dp_kernel_nb(const __half* __restrict__ cost,
                                                      float* __restrict__ out) {
    const int b = blockIdx.x;
    const int t = threadIdx.x;
    const float INF = __builtin_inff();
    const __half* Cl = cost + ((size_t)SLACK_FRONT + (size_t)b * ROW_STRIDE) * T_LEN + 16 * t;

    // DP column state (16 scalars)
    float v0 = INF, v1 = INF, v2 = INF, v3 = INF, v4 = INF, v5 = INF, v6 = INF, v7 = INF;
    float v8 = INF, v9 = INF, v10 = INF, v11 = INF, v12 = INF, v13 = INF, v14 = INF, v15 = INF;
    float right_out = INF;
    float diag_feed = INF;
    float lane0_left = -INF;   // -INF only for the very first step (r==0,t==0)

    // 8-slot register pipeline (scalar SSA, nothing indexed)
    float4 a0, b0, a1, b1, a2, b2, a3, b3, a4, b4, a5, b5, a6, b6, a7, b7;
    const __half *q0, *q1, *q2, *q3, *q4, *q5, *q6, *q7;
    INIT_SLOT(0) INIT_SLOT(1) INIT_SLOT(2) INIT_SLOT(3)
    INIT_SLOT(4) INIT_SLOT(5) INIT_SLOT(6) INIT_SLOT(7)

    // 135 chunks of 8 steps = s 0..1079
    for (int chunk = 0; chunk < 135; ++chunk) {
        DP_STEP(a0, b0) RELOAD(0)
        DP_STEP(a1, b1) RELOAD(1)
        DP_STEP(a2, b2) RELOAD(2)
        DP_STEP(a3, b3) RELOAD(3)
        DP_STEP(a4, b4) RELOAD(4)
        DP_STEP(a5, b5) RELOAD(5)
        DP_STEP(a6, b6) RELOAD(6)
        DP_STEP(a7, b7) RELOAD(7)
    }
    // remainder: s = 1080..1086, data already in slots 0..6, no reloads
    DP_STEP(a0, b0)
    DP_STEP(a1, b1)
    DP_STEP(a2, b2)
    DP_STEP(a3, b3)
    DP_STEP(a4, b4)
    DP_STEP(a5, b5)
    DP_STEP(a6, b6)

    if (t == 63) atomicAdd(out, v15 * (1.0f / (float)BATCH));
}

// ---------------------------------------------------------------------------
// Last-resort fused fallback (ws too small for strided fp16 layout).
// ---------------------------------------------------------------------------
__global__ __launch_bounds__(64) void dp_fused_kernel(const float* __restrict__ pred,
                                                      const float* __restrict__ targ,
                                                      float* __restrict__ out) {
    const int b = blockIdx.x;
    const int t = threadIdx.x;
    const float INF = __builtin_inff();
    const float* P = pred + (size_t)b * T_LEN * D_DIM;
    const float* T = targ + (size_t)b * T_LEN * D_DIM + (size_t)(16 * t) * D_DIM;

    float prev[16];
#pragma unroll
    for (int j = 0; j < 16; j++) prev[j] = INF;
    float right_out = INF;
    float diag_feed = INF;

    for (int s = 0; s < T_LEN + 63; s++) {
        int r = s - t;
        float inc = __shfl_up(right_out, 1, 64);
        float left = inc, diag = diag_feed;
        diag_feed = inc;
        if (t == 0) { left = (r == 0) ? -INF : INF; diag = INF; }
        if (r >= 0 && r < T_LEN) {
            float4 pr[16];
            const float4* pp = (const float4*)(P + (size_t)r * D_DIM);
#pragma unroll
            for (int q = 0; q < 16; q++) pr[q] = pp[q];
#pragma unroll
            for (int j = 0; j < 16; j++) {
                const float4* tp = (const float4*)(T + (size_t)j * D_DIM);
                float acc = 0.0f;
#pragma unroll
                for (int q = 0; q < 16; q++) {
                    float4 tv = tp[q];
                    float dx = pr[q].x - tv.x; acc += dx * dx;
                    float dy = pr[q].y - tv.y; acc += dy * dy;
                    float dz = pr[q].z - tv.z; acc += dz * dz;
                    float dw = pr[q].w - tv.w; acc += dw * dw;
                }
                float c = sqrtf(fmaxf(acc, 1e-12f));
                float e = fminf(prev[j], diag);
                float hm = fmaxf(e, c);
                float vv = __builtin_amdgcn_fmed3f(c, hm, left);
                diag = prev[j];
                prev[j] = vv;
                left = vv;
            }
            right_out = left;
        }
    }
    if (t == 63) atomicAdd(out, prev[15] * (1.0f / (float)BATCH));
}

extern "C" void kernel_launch(void* const* d_in, const int* in_sizes, int n_in,
                              void* d_out, int out_size, void* d_ws, size_t ws_size,
                              hipStream_t stream) {
    const float* pred = (const float*)d_in[0];
    const float* targ = (const float*)d_in[1];
    float* out = (float*)d_out;

    hipMemsetAsync(out, 0, sizeof(float) * out_size, stream);

    const size_t need_strided =
        ((size_t)BATCH * ROW_STRIDE + SLACK_BACK) * (size_t)T_LEN * sizeof(__half);  // ~71.4 MB

    if (ws_size >= need_strided) {
        __half* ws = (__half*)d_ws;
        fill_slack_kernel<<<1024, 256, 0, stream>>>(ws);
        __half* cost_base = ws + (size_t)SLACK_FRONT * T_LEN;
        dim3 grid(8, 8, BATCH);
        cost_kernel<<<grid, 256, 0, stream>>>(pred, targ, cost_base,
                                              (unsigned long long)ROW_STRIDE * T_LEN);
        dp_kernel_nb<<<BATCH, 64, 0, stream>>>(ws, out);
    } else {
        dp_fused_kernel<<<BATCH, 64, 0, stream>>>(pred, targ, out);
    }
}